// Round 1
// baseline (15977.243 us; speedup 1.0000x reference)
//
#include <hip/hip_runtime.h>
#include <hip/hip_bf16.h>
#include <hip/hip_cooperative_groups.h>

namespace cg = cooperative_groups;

#define NN 4096
#define BB 4
#define CC 1000
#define DD 2048
#define NSTEPS 100
#define DT_C 0.01f
#define TWOPI_C 6.2831853071795862f
#define INV_TWOPI_C 0.15915494309189535f

// ---------- prep kernels ----------

__global__ void build_w_kernel(const float* __restrict__ al,
                               const float* __restrict__ cm,
                               ushort* __restrict__ W) {
  size_t stride = (size_t)gridDim.x * blockDim.x;
  for (size_t i = (size_t)blockIdx.x * blockDim.x + threadIdx.x;
       i < (size_t)NN * NN; i += stride) {
    int r = (int)(i >> 12);
    int c = (int)(i & (NN - 1));
    float a = al[i];
    float sig = 1.0f / (1.0f + __expf(-a));
    float w = (r == c) ? 0.0f : sig * cm[i];
    // RNE float->bf16
    unsigned int u = __float_as_uint(w);
    unsigned int rnd = u + 0x7fffu + ((u >> 16) & 1u);
    W[i] = (ushort)(rnd >> 16);
  }
}

__global__ void zero_kernel(float* __restrict__ p, int n) {
  int i = blockIdx.x * blockDim.x + threadIdx.x;
  if (i < n) p[i] = 0.0f;
}

__global__ void enc_partial_kernel(const float* __restrict__ x,
                                   const float* __restrict__ enc_w,
                                   float* __restrict__ extacc) {
  int nblk = blockIdx.x & 15;   // 16 n-blocks of 256
  int dblk = blockIdx.x >> 4;   // 16 d-blocks of 128
  int n = nblk * 256 + threadIdx.x;
  int d0 = dblk * 128;
  float a0 = 0.f, a1 = 0.f, a2 = 0.f, a3 = 0.f;
  for (int d = d0; d < d0 + 128; ++d) {
    float w = enc_w[(size_t)d * NN + n];
    a0 = fmaf(x[d], w, a0);
    a1 = fmaf(x[DD + d], w, a1);
    a2 = fmaf(x[2 * DD + d], w, a2);
    a3 = fmaf(x[3 * DD + d], w, a3);
  }
  atomicAdd(&extacc[n], a0);
  atomicAdd(&extacc[NN + n], a1);
  atomicAdd(&extacc[2 * NN + n], a2);
  atomicAdd(&extacc[3 * NN + n], a3);
}

__global__ void enc_finish_kernel(float* __restrict__ ext,
                                  const float* __restrict__ enc_b) {
  int i = blockIdx.x * blockDim.x + threadIdx.x;
  if (i < BB * NN) ext[i] = tanhf(ext[i] + enc_b[i & (NN - 1)]);
}

// ---------- main persistent cooperative kernel ----------
// 256 WGs x 512 threads. WG w owns rows [w*16, w*16+16); 32 lanes per row.
// phi lives in registers (replicated across the row's 32 lanes).
// sin/cos vectors double-buffered in global ws; one grid sync per step.

__global__ void __launch_bounds__(512, 2) kuramoto_kernel(
    const float* __restrict__ omega,
    const float* __restrict__ init_phases,
    const float* __restrict__ readout_w,
    const float* __restrict__ readout_b,
    const float* __restrict__ Kp,
    const ushort* __restrict__ W,
    const float* __restrict__ ext,
    float* __restrict__ sbuf,   // [2][NN]
    float* __restrict__ cbuf,   // [2][NN]
    float* __restrict__ out)    // [BB][CC]
{
  cg::grid_group grid = cg::this_grid();
  const int w    = blockIdx.x;     // 0..255
  const int tid  = threadIdx.x;    // 0..511
  const int rloc = tid >> 5;       // 0..15
  const int lane = tid & 31;       // 0..31
  const int r    = w * 16 + rloc;

  const float scale = Kp[0] * (1.0f / 4096.0f);
  const float om = omega[r];

  // out = bias (d_out is poisoned before every call)
  if (w < 8) {
    int idx = w * 512 + tid;
    if (idx < BB * CC) out[idx] = readout_b[idx % CC];
  }

  float phi  = init_phases[r];
  float sphi = __sinf(phi);
  float cphi = __cosf(phi);
  if (lane == 0) { sbuf[r] = sphi; cbuf[r] = cphi; }

  const ushort* Wr = W + (size_t)r * NN + lane * 8;

  // readout mapping: 2 c-tiles of 500 x 128 j-chunks of 64
  const int ctile = w >> 7;
  const int jc    = w & 127;
  const int myc   = ctile * 500 + tid;  // valid when tid < 500

  grid.sync();

  int p = 0;
  for (int b = 0; b < BB; ++b) {
    const float ex = ext[b * NN + r];
    for (int t = 0; t < NSTEPS; ++t) {
      const float* sp = sbuf + p * NN + lane * 8;
      const float* cp = cbuf + p * NN + lane * 8;
      float ys0 = 0.f, ys1 = 0.f, yc0 = 0.f, yc1 = 0.f;
#pragma unroll
      for (int it = 0; it < 16; ++it) {
        uint4  wv  = *reinterpret_cast<const uint4*>(Wr + it * 256);
        float4 sv0 = *reinterpret_cast<const float4*>(sp + it * 256);
        float4 sv1 = *reinterpret_cast<const float4*>(sp + it * 256 + 4);
        float4 cv0 = *reinterpret_cast<const float4*>(cp + it * 256);
        float4 cv1 = *reinterpret_cast<const float4*>(cp + it * 256 + 4);
        float w0 = __uint_as_float(wv.x << 16);
        float w1 = __uint_as_float(wv.x & 0xffff0000u);
        float w2 = __uint_as_float(wv.y << 16);
        float w3 = __uint_as_float(wv.y & 0xffff0000u);
        float w4 = __uint_as_float(wv.z << 16);
        float w5 = __uint_as_float(wv.z & 0xffff0000u);
        float w6 = __uint_as_float(wv.w << 16);
        float w7 = __uint_as_float(wv.w & 0xffff0000u);
        ys0 = fmaf(w0, sv0.x, ys0); yc0 = fmaf(w0, cv0.x, yc0);
        ys1 = fmaf(w1, sv0.y, ys1); yc1 = fmaf(w1, cv0.y, yc1);
        ys0 = fmaf(w2, sv0.z, ys0); yc0 = fmaf(w2, cv0.z, yc0);
        ys1 = fmaf(w3, sv0.w, ys1); yc1 = fmaf(w3, cv0.w, yc1);
        ys0 = fmaf(w4, sv1.x, ys0); yc0 = fmaf(w4, cv1.x, yc0);
        ys1 = fmaf(w5, sv1.y, ys1); yc1 = fmaf(w5, cv1.y, yc1);
        ys0 = fmaf(w6, sv1.z, ys0); yc0 = fmaf(w6, cv1.z, yc0);
        ys1 = fmaf(w7, sv1.w, ys1); yc1 = fmaf(w7, cv1.w, yc1);
      }
      float ys = ys0 + ys1, yc = yc0 + yc1;
#pragma unroll
      for (int off = 16; off > 0; off >>= 1) {
        ys += __shfl_xor(ys, off, 32);
        yc += __shfl_xor(yc, off, 32);
      }
      float coup = cphi * ys - sphi * yc;
      phi = phi + DT_C * ((om + scale * coup) + ex);
      phi = phi - TWOPI_C * floorf(phi * INV_TWOPI_C);
      sphi = __sinf(phi);
      cphi = __cosf(phi);
      if (lane == 0) {
        sbuf[(p ^ 1) * NN + r] = sphi;
        cbuf[(p ^ 1) * NN + r] = cphi;
      }
      p ^= 1;
      grid.sync();
    }
    // readout for sample b from buffer p (concurrent-safe: steps write p^1)
    if (tid < 500) {
      const float* sb = sbuf + p * NN;
      const float* cb = cbuf + p * NN;
      float acc = 0.f;
      int j0 = jc * 64;
#pragma unroll 4
      for (int jj = 0; jj < 64; ++jj) {
        int j = j0 + jj;
        float f = (j < NN) ? sb[j] : cb[j - NN];
        acc = fmaf(f, readout_w[(size_t)j * CC + myc], acc);
      }
      atomicAdd(&out[b * CC + myc], acc);
    }
  }
}

// ---------- launch ----------

extern "C" void kernel_launch(void* const* d_in, const int* in_sizes, int n_in,
                              void* d_out, int out_size, void* d_ws, size_t ws_size,
                              hipStream_t stream) {
  const float* x           = (const float*)d_in[0];
  const float* enc_w       = (const float*)d_in[1];
  const float* enc_b       = (const float*)d_in[2];
  const float* readout_w   = (const float*)d_in[3];
  const float* readout_b   = (const float*)d_in[4];
  const float* omega       = (const float*)d_in[5];
  const float* al          = (const float*)d_in[6];
  const float* cm          = (const float*)d_in[7];
  const float* K           = (const float*)d_in[8];
  const float* init_phases = (const float*)d_in[9];
  float* out = (float*)d_out;

  char* ws = (char*)d_ws;
  ushort* W   = (ushort*)ws;                                   // 33554432 B
  float*  ext = (float*)(ws + 33554432);                       // 65536 B
  float*  sb  = (float*)(ws + 33554432 + 65536);               // 32768 B
  float*  cb  = (float*)(ws + 33554432 + 65536 + 32768);       // 32768 B

  build_w_kernel<<<4096, 256, 0, stream>>>(al, cm, W);
  zero_kernel<<<(BB * NN + 255) / 256, 256, 0, stream>>>(ext, BB * NN);
  enc_partial_kernel<<<256, 256, 0, stream>>>(x, enc_w, ext);
  enc_finish_kernel<<<(BB * NN + 255) / 256, 256, 0, stream>>>(ext, enc_b);

  void* args[] = { (void*)&omega, (void*)&init_phases, (void*)&readout_w,
                   (void*)&readout_b, (void*)&K, (void*)&W, (void*)&ext,
                   (void*)&sb, (void*)&cb, (void*)&out };
  hipLaunchCooperativeKernel((const void*)kuramoto_kernel, dim3(256), dim3(512),
                             args, 0, stream);
}

// Round 2
// 12098.145 us; speedup vs baseline: 1.3206x; 1.3206x over previous
//
#include <hip/hip_runtime.h>
#include <hip/hip_bf16.h>
#include <hip/hip_cooperative_groups.h>

namespace cgrp = cooperative_groups;

#define NN 4096
#define BB 4
#define CC 1000
#define DD 2048
#define NSTEPS 100
#define DT_C 0.01f
#define TWOPI_C 6.2831853071795862f
#define INV_TWOPI_C 0.15915494309189535f

__device__ __forceinline__ ushort f2bf(float x) {
  unsigned u = __float_as_uint(x);
  unsigned r = u + 0x7fffu + ((u >> 16) & 1u);
  return (ushort)(r >> 16);
}
__device__ __forceinline__ float bflo(unsigned u) { return __uint_as_float(u << 16); }
__device__ __forceinline__ float bfhi(unsigned u) { return __uint_as_float(u & 0xffff0000u); }

// ---------- prep kernels ----------

__global__ void build_w_kernel(const float* __restrict__ al,
                               const float* __restrict__ cm,
                               ushort* __restrict__ W) {
  size_t stride = (size_t)gridDim.x * blockDim.x;
  for (size_t i = (size_t)blockIdx.x * blockDim.x + threadIdx.x;
       i < (size_t)NN * NN; i += stride) {
    int r = (int)(i >> 12);
    int c = (int)(i & (NN - 1));
    float a = al[i];
    float sig = 1.0f / (1.0f + __expf(-a));
    float w = (r == c) ? 0.0f : sig * cm[i];
    W[i] = f2bf(w);
  }
}

__global__ void zero_kernel(float* __restrict__ p, int n) {
  int i = blockIdx.x * blockDim.x + threadIdx.x;
  if (i < n) p[i] = 0.0f;
}

__global__ void enc_partial_kernel(const float* __restrict__ x,
                                   const float* __restrict__ enc_w,
                                   float* __restrict__ extacc) {
  int nblk = blockIdx.x & 15;
  int dblk = blockIdx.x >> 4;
  int n = nblk * 256 + threadIdx.x;
  int d0 = dblk * 128;
  float a0 = 0.f, a1 = 0.f, a2 = 0.f, a3 = 0.f;
  for (int d = d0; d < d0 + 128; ++d) {
    float w = enc_w[(size_t)d * NN + n];
    a0 = fmaf(x[d], w, a0);
    a1 = fmaf(x[DD + d], w, a1);
    a2 = fmaf(x[2 * DD + d], w, a2);
    a3 = fmaf(x[3 * DD + d], w, a3);
  }
  atomicAdd(&extacc[n], a0);
  atomicAdd(&extacc[NN + n], a1);
  atomicAdd(&extacc[2 * NN + n], a2);
  atomicAdd(&extacc[3 * NN + n], a3);
}

__global__ void enc_finish_kernel(float* __restrict__ ext,
                                  const float* __restrict__ enc_b) {
  int i = blockIdx.x * blockDim.x + threadIdx.x;
  if (i < BB * NN) ext[i] = tanhf(ext[i] + enc_b[i & (NN - 1)]);
}

// ---------- main persistent cooperative kernel ----------
// 256 WGs x 512 threads (8 waves). WG w owns rows [w*16, w*16+16).
// Wave v owns rows 2v, 2v+1. W rows live in LDS (128 KB, staged once).
// sin/cos (bf16) staged into LDS each step (16 KB). phi in registers.
// Published state: global bf16 s/c double buffers; one grid.sync per step.

__global__ void __launch_bounds__(512, 1) kuramoto_kernel(
    const float* __restrict__ omega,
    const float* __restrict__ init_phases,
    const float* __restrict__ readout_w,
    const float* __restrict__ readout_b,
    const float* __restrict__ Kp,
    const ushort* __restrict__ Wg,
    const float* __restrict__ ext,
    ushort* __restrict__ sgb,   // [2][NN] bf16
    ushort* __restrict__ cgb,   // [2][NN] bf16
    float* __restrict__ out)    // [BB][CC]
{
  cgrp::grid_group grid = cgrp::this_grid();
  extern __shared__ char smem[];
  ushort* Wl = (ushort*)smem;              // [16][4096] bf16 = 128 KB
  ushort* sl = (ushort*)(smem + 131072);   // [4096] bf16 = 8 KB
  ushort* cl = (ushort*)(smem + 139264);   // [4096] bf16 = 8 KB

  const int w    = blockIdx.x;     // 0..255
  const int tid  = threadIdx.x;    // 0..511
  const int wv   = tid >> 6;       // wave 0..7
  const int lane = tid & 63;       // 0..63
  const int rA   = wv * 2;         // local row A (B = rA+1)
  const int gA   = w * 16 + rA;    // global row A

  // one-time: stage this WG's 16 rows of W into LDS (coalesced b128)
  {
    const uint4* src = (const uint4*)(Wg + (size_t)w * 16 * NN);
    uint4* dst = (uint4*)Wl;
    for (int i = tid; i < 8192; i += 512) dst[i] = src[i];
  }

  const float scale = Kp[0] * (1.0f / 4096.0f);
  const float omA = omega[gA], omB = omega[gA + 1];
  float phiA = init_phases[gA], phiB = init_phases[gA + 1];
  float sA, cA, sB, cB;
  __sincosf(phiA, &sA, &cA);
  __sincosf(phiB, &sB, &cB);
  if (lane == 0) {
    ((unsigned*)sgb)[gA >> 1] = (unsigned)f2bf(sA) | ((unsigned)f2bf(sB) << 16);
    ((unsigned*)cgb)[gA >> 1] = (unsigned)f2bf(cA) | ((unsigned)f2bf(cB) << 16);
  }
  // out = bias (d_out re-poisoned before every call)
  if (w < 8) {
    int idx = w * 512 + tid;
    if (idx < BB * CC) out[idx] = readout_b[idx % CC];
  }
  // readout mapping: 2 c-tiles x 128 j-chunks
  const int ctile = w >> 7, jc = w & 127, myc = ctile * 500 + tid;

  grid.sync();

  int p = 0;
  for (int b = 0; b < BB; ++b) {
    const float exA = ext[b * NN + gA], exB = ext[b * NN + gA + 1];
    for (int t = 0; t < NSTEPS; ++t) {
      // stage current s/c (bf16) into LDS: 512 threads x 16 B each
      {
        const uint4* s4 = (const uint4*)(sgb + p * NN);
        const uint4* c4 = (const uint4*)(cgb + p * NN);
        ((uint4*)sl)[tid] = s4[tid];
        ((uint4*)cl)[tid] = c4[tid];
      }
      __syncthreads();

      float ysA = 0.f, ycA = 0.f, ysB = 0.f, ycB = 0.f;
      const ushort* WA = Wl + rA * NN;
      const ushort* WB = WA + NN;
#pragma unroll
      for (int k = 0; k < 8; ++k) {
        int j = k * 512 + lane * 8;
        uint4 sv = *(const uint4*)(sl + j);
        uint4 cv = *(const uint4*)(cl + j);
        uint4 wa = *(const uint4*)(WA + j);
        uint4 wb = *(const uint4*)(WB + j);
#define FMA_U32(WAU, WBU, SU, CU)                                   \
        {                                                           \
          float w0 = bflo(WAU), w1 = bfhi(WAU);                     \
          float v0 = bflo(WBU), v1 = bfhi(WBU);                     \
          float s0 = bflo(SU),  s1 = bfhi(SU);                      \
          float q0 = bflo(CU),  q1 = bfhi(CU);                      \
          ysA = fmaf(w0, s0, ysA); ycA = fmaf(w0, q0, ycA);         \
          ysB = fmaf(v0, s0, ysB); ycB = fmaf(v0, q0, ycB);         \
          ysA = fmaf(w1, s1, ysA); ycA = fmaf(w1, q1, ycA);         \
          ysB = fmaf(v1, s1, ysB); ycB = fmaf(v1, q1, ycB);         \
        }
        FMA_U32(wa.x, wb.x, sv.x, cv.x)
        FMA_U32(wa.y, wb.y, sv.y, cv.y)
        FMA_U32(wa.z, wb.z, sv.z, cv.z)
        FMA_U32(wa.w, wb.w, sv.w, cv.w)
#undef FMA_U32
      }
      // butterfly over the full wave (commutative adds -> bit-identical per lane)
#pragma unroll
      for (int off = 32; off > 0; off >>= 1) {
        ysA += __shfl_xor(ysA, off);
        ycA += __shfl_xor(ycA, off);
        ysB += __shfl_xor(ysB, off);
        ycB += __shfl_xor(ycB, off);
      }
      float coupA = cA * ysA - sA * ycA;
      float coupB = cB * ysB - sB * ycB;
      phiA = phiA + DT_C * ((omA + scale * coupA) + exA);
      phiB = phiB + DT_C * ((omB + scale * coupB) + exB);
      phiA = phiA - TWOPI_C * floorf(phiA * INV_TWOPI_C);
      phiB = phiB - TWOPI_C * floorf(phiB * INV_TWOPI_C);
      __sincosf(phiA, &sA, &cA);
      __sincosf(phiB, &sB, &cB);
      if (lane == 0) {
        ((unsigned*)(sgb + (p ^ 1) * NN))[gA >> 1] =
            (unsigned)f2bf(sA) | ((unsigned)f2bf(sB) << 16);
        ((unsigned*)(cgb + (p ^ 1) * NN))[gA >> 1] =
            (unsigned)f2bf(cA) | ((unsigned)f2bf(cB) << 16);
      }
      grid.sync();
      p ^= 1;
    }
    // readout for sample b from published buffer p (bf16)
    if (tid < 500) {
      float acc = 0.f;
      int j0 = jc * 64;
#pragma unroll 4
      for (int jj = 0; jj < 64; ++jj) {
        int j = j0 + jj;
        float f = (j < NN)
            ? __uint_as_float((unsigned)sgb[p * NN + j] << 16)
            : __uint_as_float((unsigned)cgb[p * NN + j - NN] << 16);
        acc = fmaf(f, readout_w[(size_t)j * CC + myc], acc);
      }
      atomicAdd(&out[b * CC + myc], acc);
    }
  }
}

// ---------- launch ----------

extern "C" void kernel_launch(void* const* d_in, const int* in_sizes, int n_in,
                              void* d_out, int out_size, void* d_ws, size_t ws_size,
                              hipStream_t stream) {
  const float* x           = (const float*)d_in[0];
  const float* enc_w       = (const float*)d_in[1];
  const float* enc_b       = (const float*)d_in[2];
  const float* readout_w   = (const float*)d_in[3];
  const float* readout_b   = (const float*)d_in[4];
  const float* omega       = (const float*)d_in[5];
  const float* al          = (const float*)d_in[6];
  const float* cm          = (const float*)d_in[7];
  const float* K           = (const float*)d_in[8];
  const float* init_phases = (const float*)d_in[9];
  float* out = (float*)d_out;

  char* ws = (char*)d_ws;
  ushort* W   = (ushort*)ws;                             // 33554432 B
  float*  ext = (float*)(ws + 33554432);                 // 65536 B
  ushort* sgb = (ushort*)(ws + 33554432 + 65536);        // 16384 B ([2][4096] bf16)
  ushort* cgb = (ushort*)(ws + 33554432 + 65536 + 16384);// 16384 B

  build_w_kernel<<<4096, 256, 0, stream>>>(al, cm, W);
  zero_kernel<<<(BB * NN + 255) / 256, 256, 0, stream>>>(ext, BB * NN);
  enc_partial_kernel<<<256, 256, 0, stream>>>(x, enc_w, ext);
  enc_finish_kernel<<<(BB * NN + 255) / 256, 256, 0, stream>>>(ext, enc_b);

  void* args[] = { (void*)&omega, (void*)&init_phases, (void*)&readout_w,
                   (void*)&readout_b, (void*)&K, (void*)&W, (void*)&ext,
                   (void*)&sgb, (void*)&cgb, (void*)&out };
  hipLaunchCooperativeKernel((const void*)kuramoto_kernel, dim3(256), dim3(512),
                             args, 147456, stream);
}

// Round 3
// 2681.586 us; speedup vs baseline: 5.9581x; 4.5116x over previous
//
#include <hip/hip_runtime.h>

#define NN 4096
#define BB 4
#define CC 1000
#define DD 2048
#define NSTEPS 100
#define DT_C 0.01f
#define TWOPI_C 6.2831853071795862f
#define INV_TWOPI_C 0.15915494309189535f

typedef unsigned long long u64;

__device__ __forceinline__ ushort f2bf(float x) {
  unsigned u = __float_as_uint(x);
  unsigned r = u + 0x7fffu + ((u >> 16) & 1u);
  return (ushort)(r >> 16);
}
__device__ __forceinline__ float bflo(unsigned u) { return __uint_as_float(u << 16); }
__device__ __forceinline__ float bfhi(unsigned u) { return __uint_as_float(u & 0xffff0000u); }

// ---------- prep kernels ----------

__global__ void build_w_kernel(const float* __restrict__ al,
                               const float* __restrict__ cm,
                               ushort* __restrict__ W) {
  size_t stride = (size_t)gridDim.x * blockDim.x;
  for (size_t i = (size_t)blockIdx.x * blockDim.x + threadIdx.x;
       i < (size_t)NN * NN; i += stride) {
    int r = (int)(i >> 12);
    int c = (int)(i & (NN - 1));
    float a = al[i];
    float sig = 1.0f / (1.0f + __expf(-a));
    float w = (r == c) ? 0.0f : sig * cm[i];
    W[i] = f2bf(w);
  }
}

__global__ void zero_kernel(float* __restrict__ p, int n) {
  int i = blockIdx.x * blockDim.x + threadIdx.x;
  if (i < n) p[i] = 0.0f;
}

__global__ void enc_partial_kernel(const float* __restrict__ x,
                                   const float* __restrict__ enc_w,
                                   float* __restrict__ extacc) {
  int nblk = blockIdx.x & 15;
  int dblk = blockIdx.x >> 4;
  int n = nblk * 256 + threadIdx.x;
  int d0 = dblk * 128;
  float a0 = 0.f, a1 = 0.f, a2 = 0.f, a3 = 0.f;
  for (int d = d0; d < d0 + 128; ++d) {
    float w = enc_w[(size_t)d * NN + n];
    a0 = fmaf(x[d], w, a0);
    a1 = fmaf(x[DD + d], w, a1);
    a2 = fmaf(x[2 * DD + d], w, a2);
    a3 = fmaf(x[3 * DD + d], w, a3);
  }
  atomicAdd(&extacc[n], a0);
  atomicAdd(&extacc[NN + n], a1);
  atomicAdd(&extacc[2 * NN + n], a2);
  atomicAdd(&extacc[3 * NN + n], a3);
}

__global__ void enc_finish_kernel(float* __restrict__ ext,
                                  const float* __restrict__ enc_b) {
  int i = blockIdx.x * blockDim.x + threadIdx.x;
  if (i < BB * NN) ext[i] = tanhf(ext[i] + enc_b[i & (NN - 1)]);
}

__global__ void out_init_kernel(float* __restrict__ out,
                                const float* __restrict__ rb) {
  int i = blockIdx.x * blockDim.x + threadIdx.x;
  if (i < BB * CC) out[i] = rb[i % CC];
}

// ---------- main persistent kernel: dataflow-synced, NO grid barrier ----------
// 256 WGs x 512 threads (8 waves). WG w owns rows [w*16, w*16+16); wave v owns
// rows 2v, 2v+1 (phi replicated across the wave's 64 lanes). W rows in LDS
// (128 KB, staged once). Per-step state record per row: 8 B = {tag=step+1 |
// packed bf16 (c<<16|s)} in an 8-deep ring, written/read with agent-scope
// relaxed atomics (tag travels with data -> no fences needed). WG skew is
// bounded by the dataflow (<=2 steps), ring of 8 is safe; 0xAA poison never
// matches tags 1..401.

__global__ void __launch_bounds__(512, 1) kuramoto_kernel(
    const float* __restrict__ omega,
    const float* __restrict__ init_phases,
    const float* __restrict__ readout_w,
    const float* __restrict__ Kp,
    const ushort* __restrict__ Wg,
    const float* __restrict__ ext,
    u64* __restrict__ ring,      // [8][NN] records
    float* __restrict__ out)     // [BB][CC], pre-initialized with bias
{
  extern __shared__ char smem[];
  ushort* Wl = (ushort*)smem;              // [16][4096] bf16 = 128 KB
  ushort* sl = (ushort*)(smem + 131072);   // [4096] bf16 = 8 KB
  ushort* cl = (ushort*)(smem + 139264);   // [4096] bf16 = 8 KB

  const int w    = blockIdx.x;     // 0..255
  const int tid  = threadIdx.x;    // 0..511
  const int wv   = tid >> 6;       // wave 0..7
  const int lane = tid & 63;       // 0..63
  const int rA   = wv * 2;
  const int gA   = w * 16 + rA;

  // one-time: stage this WG's 16 rows of W into LDS
  {
    const uint4* src = (const uint4*)(Wg + (size_t)w * 16 * NN);
    uint4* dst = (uint4*)Wl;
    for (int i = tid; i < 8192; i += 512) dst[i] = src[i];
  }

  const float scale = Kp[0] * (1.0f / 4096.0f);
  const float omA = omega[gA], omB = omega[gA + 1];
  float phiA = init_phases[gA], phiB = init_phases[gA + 1];
  float sA, cA, sB, cB;
  __sincosf(phiA, &sA, &cA);
  __sincosf(phiB, &sB, &cB);

  // publish initial state with tag 1
  if (lane < 2) {
    unsigned data = lane ? ((unsigned)f2bf(sB) | ((unsigned)f2bf(cB) << 16))
                         : ((unsigned)f2bf(sA) | ((unsigned)f2bf(cA) << 16));
    u64 rec = ((u64)1u << 32) | data;
    __hip_atomic_store(ring + (size_t)(1 & 7) * NN + gA + lane, rec,
                       __ATOMIC_RELAXED, __HIP_MEMORY_SCOPE_AGENT);
  }

  // readout mapping: 2 c-tiles x 128 j-chunks of 64 features
  const int ctile = w >> 7, jc = w & 127, myc = ctile * 500 + tid;

  auto readout = [&](int bb) {
    float acc = 0.f;
    int j0 = jc * 64;
#pragma unroll 8
    for (int jj = 0; jj < 64; ++jj) {
      int j = j0 + jj;
      float f = (j < NN) ? __uint_as_float((unsigned)sl[j] << 16)
                         : __uint_as_float((unsigned)cl[j - NN] << 16);
      acc = fmaf(f, readout_w[(size_t)j * CC + myc], acc);
    }
    atomicAdd(&out[bb * CC + myc], acc);
  };

  int tag = 1;
  for (int b = 0; b < BB; ++b) {
    const float exA = ext[b * NN + gA], exB = ext[b * NN + gA + 1];
    for (int t = 0; t < NSTEPS; ++t) {
      // ---- stage: poll this step's 4096 records, unpack to sl/cl ----
      {
        const u64* src = ring + (size_t)(tag & 7) * NN + tid * 8;
        u64 v0, v1, v2, v3, v4, v5, v6, v7;
        unsigned pend = 0xffu;
        while (pend) {
#define POLL(I, V)                                                          \
          if (pend & (1u << I)) {                                           \
            u64 x = __hip_atomic_load(src + I, __ATOMIC_RELAXED,            \
                                      __HIP_MEMORY_SCOPE_AGENT);            \
            if ((unsigned)(x >> 32) == (unsigned)tag) {                     \
              V = x; pend &= ~(1u << I);                                    \
            }                                                               \
          }
          POLL(0, v0) POLL(1, v1) POLL(2, v2) POLL(3, v3)
          POLL(4, v4) POLL(5, v5) POLL(6, v6) POLL(7, v7)
#undef POLL
        }
        unsigned q0 = (unsigned)v0, q1 = (unsigned)v1, q2 = (unsigned)v2,
                 q3 = (unsigned)v3, q4 = (unsigned)v4, q5 = (unsigned)v5,
                 q6 = (unsigned)v6, q7 = (unsigned)v7;
        uint4 su, cu;
        su.x = (q0 & 0xffffu) | (q1 << 16);
        cu.x = (q0 >> 16) | (q1 & 0xffff0000u);
        su.y = (q2 & 0xffffu) | (q3 << 16);
        cu.y = (q2 >> 16) | (q3 & 0xffff0000u);
        su.z = (q4 & 0xffffu) | (q5 << 16);
        cu.z = (q4 >> 16) | (q5 & 0xffff0000u);
        su.w = (q6 & 0xffffu) | (q7 << 16);
        cu.w = (q6 >> 16) | (q7 & 0xffff0000u);
        ((uint4*)sl)[tid] = su;
        ((uint4*)cl)[tid] = cu;
      }
      __syncthreads();

      // ---- dual matvec for rows rA, rA+1 from LDS ----
      float ysA = 0.f, ycA = 0.f, ysB = 0.f, ycB = 0.f;
      const ushort* WA = Wl + rA * NN;
      const ushort* WB = WA + NN;
#pragma unroll
      for (int k = 0; k < 8; ++k) {
        int j = k * 512 + lane * 8;
        uint4 sv = *(const uint4*)(sl + j);
        uint4 cv = *(const uint4*)(cl + j);
        uint4 wa = *(const uint4*)(WA + j);
        uint4 wb = *(const uint4*)(WB + j);
#define FMA_U32(WAU, WBU, SU, CU)                                   \
        {                                                           \
          float w0 = bflo(WAU), w1 = bfhi(WAU);                     \
          float v0 = bflo(WBU), v1 = bfhi(WBU);                     \
          float s0 = bflo(SU),  s1 = bfhi(SU);                      \
          float c0 = bflo(CU),  c1 = bfhi(CU);                      \
          ysA = fmaf(w0, s0, ysA); ycA = fmaf(w0, c0, ycA);         \
          ysB = fmaf(v0, s0, ysB); ycB = fmaf(v0, c0, ycB);         \
          ysA = fmaf(w1, s1, ysA); ycA = fmaf(w1, c1, ycA);         \
          ysB = fmaf(v1, s1, ysB); ycB = fmaf(v1, c1, ycB);         \
        }
        FMA_U32(wa.x, wb.x, sv.x, cv.x)
        FMA_U32(wa.y, wb.y, sv.y, cv.y)
        FMA_U32(wa.z, wb.z, sv.z, cv.z)
        FMA_U32(wa.w, wb.w, sv.w, cv.w)
#undef FMA_U32
      }
#pragma unroll
      for (int off = 32; off > 0; off >>= 1) {
        ysA += __shfl_xor(ysA, off);
        ycA += __shfl_xor(ycA, off);
        ysB += __shfl_xor(ysB, off);
        ycB += __shfl_xor(ycB, off);
      }
      float coupA = cA * ysA - sA * ycA;
      float coupB = cB * ysB - sB * ycB;
      phiA = phiA + DT_C * ((omA + scale * coupA) + exA);
      phiB = phiB + DT_C * ((omB + scale * coupB) + exB);
      phiA = phiA - TWOPI_C * floorf(phiA * INV_TWOPI_C);
      phiB = phiB - TWOPI_C * floorf(phiB * INV_TWOPI_C);
      __sincosf(phiA, &sA, &cA);
      __sincosf(phiB, &sB, &cB);

      // ---- publish new state (tag+1) ----
      if (lane < 2) {
        unsigned data = lane ? ((unsigned)f2bf(sB) | ((unsigned)f2bf(cB) << 16))
                             : ((unsigned)f2bf(sA) | ((unsigned)f2bf(cA) << 16));
        u64 rec = ((u64)(unsigned)(tag + 1) << 32) | data;
        __hip_atomic_store(ring + (size_t)((tag + 1) & 7) * NN + gA + lane, rec,
                           __ATOMIC_RELAXED, __HIP_MEMORY_SCOPE_AGENT);
      }

      // ---- readout of previous sample (state b*100 is staged at t==0) ----
      if (t == 0 && b > 0 && tid < 500) readout(b - 1);

      __syncthreads();
      ++tag;
    }
  }

  // epilogue: stage final state (tag == 401) and read out sample 3
  {
    const u64* src = ring + (size_t)(tag & 7) * NN + tid * 8;
    u64 v0, v1, v2, v3, v4, v5, v6, v7;
    unsigned pend = 0xffu;
    while (pend) {
#define POLL(I, V)                                                          \
      if (pend & (1u << I)) {                                               \
        u64 x = __hip_atomic_load(src + I, __ATOMIC_RELAXED,                \
                                  __HIP_MEMORY_SCOPE_AGENT);                \
        if ((unsigned)(x >> 32) == (unsigned)tag) { V = x; pend &= ~(1u << I); } \
      }
      POLL(0, v0) POLL(1, v1) POLL(2, v2) POLL(3, v3)
      POLL(4, v4) POLL(5, v5) POLL(6, v6) POLL(7, v7)
#undef POLL
    }
    unsigned q0 = (unsigned)v0, q1 = (unsigned)v1, q2 = (unsigned)v2,
             q3 = (unsigned)v3, q4 = (unsigned)v4, q5 = (unsigned)v5,
             q6 = (unsigned)v6, q7 = (unsigned)v7;
    uint4 su, cu;
    su.x = (q0 & 0xffffu) | (q1 << 16);
    cu.x = (q0 >> 16) | (q1 & 0xffff0000u);
    su.y = (q2 & 0xffffu) | (q3 << 16);
    cu.y = (q2 >> 16) | (q3 & 0xffff0000u);
    su.z = (q4 & 0xffffu) | (q5 << 16);
    cu.z = (q4 >> 16) | (q5 & 0xffff0000u);
    su.w = (q6 & 0xffffu) | (q7 << 16);
    cu.w = (q6 >> 16) | (q7 & 0xffff0000u);
    ((uint4*)sl)[tid] = su;
    ((uint4*)cl)[tid] = cu;
  }
  __syncthreads();
  if (tid < 500) readout(BB - 1);
}

// ---------- launch ----------

extern "C" void kernel_launch(void* const* d_in, const int* in_sizes, int n_in,
                              void* d_out, int out_size, void* d_ws, size_t ws_size,
                              hipStream_t stream) {
  const float* x           = (const float*)d_in[0];
  const float* enc_w       = (const float*)d_in[1];
  const float* enc_b       = (const float*)d_in[2];
  const float* readout_w   = (const float*)d_in[3];
  const float* readout_b   = (const float*)d_in[4];
  const float* omega       = (const float*)d_in[5];
  const float* al          = (const float*)d_in[6];
  const float* cm          = (const float*)d_in[7];
  const float* K           = (const float*)d_in[8];
  const float* init_phases = (const float*)d_in[9];
  float* out = (float*)d_out;

  char* ws = (char*)d_ws;
  ushort* W    = (ushort*)ws;                              // 33554432 B
  float*  ext  = (float*)(ws + 33554432);                  // 65536 B
  u64*    ring = (u64*)(ws + 33554432 + 65536);            // 8*4096*8 = 262144 B

  build_w_kernel<<<4096, 256, 0, stream>>>(al, cm, W);
  zero_kernel<<<(BB * NN + 255) / 256, 256, 0, stream>>>(ext, BB * NN);
  enc_partial_kernel<<<256, 256, 0, stream>>>(x, enc_w, ext);
  enc_finish_kernel<<<(BB * NN + 255) / 256, 256, 0, stream>>>(ext, enc_b);
  out_init_kernel<<<(BB * CC + 255) / 256, 256, 0, stream>>>(out, readout_b);

  void* args[] = { (void*)&omega, (void*)&init_phases, (void*)&readout_w,
                   (void*)&K, (void*)&W, (void*)&ext, (void*)&ring, (void*)&out };
  hipLaunchCooperativeKernel((const void*)kuramoto_kernel, dim3(256), dim3(512),
                             args, 147456, stream);
}